// Round 7
// baseline (937.867 us; speedup 1.0000x reference)
//
#include <hip/hip_runtime.h>
#include <hip/hip_bf16.h>

typedef __bf16 bf16_t;
typedef __bf16 bf16x8 __attribute__((ext_vector_type(8)));
typedef __bf16 bf16x4 __attribute__((ext_vector_type(4)));
typedef float f32x4 __attribute__((ext_vector_type(4)));

constexpr int D = 128;            // NODEMB == HIDDEN == EDGEMB
constexpr int NEDGES = 800000;
constexpr int NNODES = 50000;

constexpr int WUS = 168;          // K-stride for w1dt/w1st: 160 used (5x32), +8 pad
constexpr int W2S = 136;          // K-stride for W2T: 128 used, +8 pad
constexpr int WU_ELEMS = D * WUS; // 21504
constexpr int W2_ELEMS = D * W2S; // 17408
constexpr int TILE_EDGES = 128;   // 8 waves x 16 edges
constexpr int NTILES = NEDGES / TILE_EDGES;   // 6250
constexpr int NODE_TILES = NNODES / 16;       // 3125

// ---------------------------------------------------------------------------
// Module-global tables (allocated at .so load — graph-capture safe; rebuilt
// from restored inputs every launch).
// ---------------------------------------------------------------------------
__device__ __align__(16) bf16_t g_w1dt[WU_ELEMS];  // [j][k] dst-half of W1 (+b1 row)
__device__ __align__(16) bf16_t g_w1st[WU_ELEMS];  // [j][k] src-half of W1
__device__ __align__(16) bf16_t g_w2t[W2_ELEMS];   // [n][k]
__device__ __align__(16) bf16_t g_wd[D];           // W1 distance row
__device__ __align__(16) bf16_t g_u[(size_t)NNODES * D];  // u[n] = W1d^T x_n + b1
__device__ __align__(16) bf16_t g_v[(size_t)NNODES * D];  // v[n] = W1s^T x_n

__device__ __forceinline__ bf16x8 cvt8(f32x4 lo, f32x4 hi) {
    bf16x8 t;
    t[0] = (bf16_t)lo[0]; t[1] = (bf16_t)lo[1]; t[2] = (bf16_t)lo[2]; t[3] = (bf16_t)lo[3];
    t[4] = (bf16_t)hi[0]; t[5] = (bf16_t)hi[1]; t[6] = (bf16_t)hi[2]; t[7] = (bf16_t)hi[3];
    return t;
}

// ---------------------------------------------------------------------------
// Prep 1: weight tables (unchanged from R6 — verified).
// ---------------------------------------------------------------------------
__global__ void prep_w(const float* __restrict__ W1, const float* __restrict__ b1,
                       const float* __restrict__ W2) {
    int i = blockIdx.x * blockDim.x + threadIdx.x;
    if (i < WU_ELEMS) {
        int j = i / WUS, k = i - j * WUS;
        float v = 0.f;
        if (k < 128)       v = W1[(2 + k) * D + j];
        else if (k == 128) v = W1[0 * D + j];
        else if (k == 129) v = W1[1 * D + j];
        else if (k == 130) v = b1[j];
        g_w1dt[j * WUS + k] = (bf16_t)v;
    } else if (i < 2 * WU_ELEMS) {
        int t = i - WU_ELEMS;
        int j = t / WUS, k = t - j * WUS;
        float v = 0.f;
        if (k < 128)       v = W1[(132 + k) * D + j];
        else if (k == 128) v = W1[130 * D + j];
        else if (k == 129) v = W1[131 * D + j];
        g_w1st[j * WUS + k] = (bf16_t)v;
    } else if (i < 2 * WU_ELEMS + W2_ELEMS) {
        int t = i - 2 * WU_ELEMS;
        int n = t / W2S, k = t - n * W2S;
        float v = (k < 128) ? W2[k * D + n] : 0.f;
        g_w2t[n * W2S + k] = (bf16_t)v;
    } else if (i < 2 * WU_ELEMS + W2_ELEMS + D) {
        int j = i - (2 * WU_ELEMS + W2_ELEMS);
        g_wd[j] = (bf16_t)W1[260 * D + j];
    }
}

// ---------------------------------------------------------------------------
// Prep 2: per-node u/v via MFMA (unchanged from R6 — verified).
// ---------------------------------------------------------------------------
__global__ __launch_bounds__(512, 4) void prep_uv(const float* __restrict__ nh,
                                                  const float* __restrict__ nf) {
    __shared__ bf16_t sWd[WU_ELEMS];  // 43,008 B
    __shared__ bf16_t sWs[WU_ELEMS];  // 43,008 B

    const int tid = threadIdx.x;
    {
        const uint4* gd = (const uint4*)g_w1dt;
        const uint4* gs = (const uint4*)g_w1st;
        uint4* ld = (uint4*)sWd;
        uint4* ls = (uint4*)sWs;
        for (int i = tid; i < WU_ELEMS / 8; i += 512) { ld[i] = gd[i]; ls[i] = gs[i]; }
    }
    __syncthreads();

    const int wid  = tid >> 6;
    const int lane = tid & 63;
    const int r    = lane & 15;
    const int g    = lane >> 4;

    for (int t = blockIdx.x * 8 + wid; t < NODE_TILES; t += (int)gridDim.x * 8) {
        const int n = t * 16 + r;
        const f32x4* xp = (const f32x4*)(nh + (size_t)n * D);

        bf16x8 a[5];
        #pragma unroll
        for (int ks = 0; ks < 4; ++ks)
            a[ks] = cvt8(xp[ks * 8 + g * 2], xp[ks * 8 + g * 2 + 1]);
        {
            bf16x8 tt;
            #pragma unroll
            for (int j = 0; j < 8; ++j) tt[j] = (bf16_t)0.f;
            if (g == 0) {           // k=128,129 feat; k=130 the "1" for b1 row
                tt[0] = (bf16_t)nf[2 * n];
                tt[1] = (bf16_t)nf[2 * n + 1];
                tt[2] = (bf16_t)1.f;
            }
            a[4] = tt;
        }

        f32x4 au[8], av[8];
        #pragma unroll
        for (int nt = 0; nt < 8; ++nt) {
            au[nt][0]=0.f; au[nt][1]=0.f; au[nt][2]=0.f; au[nt][3]=0.f;
            av[nt][0]=0.f; av[nt][1]=0.f; av[nt][2]=0.f; av[nt][3]=0.f;
        }
        #pragma unroll
        for (int ks = 0; ks < 5; ++ks) {
            #pragma unroll
            for (int nt = 0; nt < 8; ++nt) {
                bf16x8 wd_ = *(const bf16x8*)&sWd[(nt * 16 + r) * WUS + ks * 32 + g * 8];
                au[nt] = __builtin_amdgcn_mfma_f32_16x16x32_bf16(wd_, a[ks], au[nt], 0, 0, 0);
                bf16x8 ws_ = *(const bf16x8*)&sWs[(nt * 16 + r) * WUS + ks * 32 + g * 8];
                av[nt] = __builtin_amdgcn_mfma_f32_16x16x32_bf16(ws_, a[ks], av[nt], 0, 0, 0);
            }
        }

        bf16_t* up = g_u + (size_t)n * D;
        bf16_t* vp = g_v + (size_t)n * D;
        #pragma unroll
        for (int nt = 0; nt < 8; ++nt) {
            bf16x4 pu, pv;
            #pragma unroll
            for (int i = 0; i < 4; ++i) { pu[i] = (bf16_t)au[nt][i]; pv[i] = (bf16_t)av[nt][i]; }
            *(bf16x4*)&up[nt * 16 + g * 4] = pu;
            *(bf16x4*)&vp[nt * 16 + g * 4] = pv;
        }
    }
}

// ---------------------------------------------------------------------------
// Main edge kernel, R7: R6 + 1-tile register-prefetch pipeline.
// Tile t+1's idx/dist/u/v gathers are issued BEFORE tile t's compute, so each
// wave keeps ~8 vector loads in flight during the MFMA phase instead of
// issuing bursts and stalling on vmcnt(0).
// ---------------------------------------------------------------------------
__global__ __launch_bounds__(512, 4) void edge_mlp(
    const int* __restrict__ src_idx,
    const int* __restrict__ dst_idx,
    const float* __restrict__ distance,
    const float* __restrict__ b2,
    float* __restrict__ out)
{
    __shared__ bf16_t sW2[W2_ELEMS];   // 34,816 B
    __shared__ float  sB2[D];          //     512 B
    __shared__ bf16_t sWD[D];          //     256 B

    const int tid = threadIdx.x;
    {
        const uint4* g2 = (const uint4*)g_w2t;
        uint4* l2 = (uint4*)sW2;
        for (int i = tid; i < W2_ELEMS / 8; i += 512) l2[i] = g2[i];
        if (tid < D) { sB2[tid] = b2[tid]; sWD[tid] = g_wd[tid]; }
    }
    __syncthreads();

    const int wid  = tid >> 6;
    const int lane = tid & 63;
    const int r    = lane & 15;
    const int g    = lane >> 4;

    const int stride = (int)gridDim.x;
    const int eoff = wid * 16 + r;

    // ---- prologue: tile 0 of this block ----
    int tile = blockIdx.x;
    int e  = tile * TILE_EDGES + eoff;
    int di = dst_idx[e];
    int si = src_idx[e];
    float dist = distance[e];
    bf16x8 uf[4], vf[4];
    {
        const bf16x8* up = (const bf16x8*)(g_u + (size_t)di * D);
        const bf16x8* vp = (const bf16x8*)(g_v + (size_t)si * D);
        #pragma unroll
        for (int ks = 0; ks < 4; ++ks) uf[ks] = up[ks * 4 + g];
        #pragma unroll
        for (int ks = 0; ks < 4; ++ks) vf[ks] = vp[ks * 4 + g];
    }

    for (; tile < NTILES; tile += stride) {
        // ---- issue NEXT tile's loads (in flight during this tile's compute) ----
        int tn = tile + stride;
        int en = (tn < NTILES ? tn : tile) * TILE_EDGES + eoff;  // clamp: re-read valid mem
        int diN = dst_idx[en];
        int siN = src_idx[en];
        float distN = distance[en];
        bf16x8 ufN[4], vfN[4];
        {
            const bf16x8* upN = (const bf16x8*)(g_u + (size_t)diN * D);
            const bf16x8* vpN = (const bf16x8*)(g_v + (size_t)siN * D);
            #pragma unroll
            for (int ks = 0; ks < 4; ++ks) ufN[ks] = upN[ks * 4 + g];
            #pragma unroll
            for (int ks = 0; ks < 4; ++ks) vfN[ks] = vpN[ks * 4 + g];
        }

        // ---- h fragment: relu(u + v + dist*wd), already in B-operand layout ----
        bf16x8 hb[4];
        #pragma unroll
        for (int ks = 0; ks < 4; ++ks) {
            bf16x8 wdf = *(const bf16x8*)&sWD[ks * 32 + g * 8];
            #pragma unroll
            for (int j = 0; j < 8; ++j) {
                float h = (float)uf[ks][j] + (float)vf[ks][j] + dist * (float)wdf[j];
                hb[ks][j] = (bf16_t)(h > 0.f ? h : 0.f);
            }
        }

        // ---- layer 2 (swapped): lane (r,g) -> out[e][nt*16+g*4+i] ----
        f32x4 acc2[8];
        #pragma unroll
        for (int nt = 0; nt < 8; ++nt)
            acc2[nt] = *(const f32x4*)&sB2[nt * 16 + g * 4];
        #pragma unroll
        for (int ks = 0; ks < 4; ++ks) {
            #pragma unroll
            for (int nt = 0; nt < 8; ++nt) {
                bf16x8 w = *(const bf16x8*)&sW2[(nt * 16 + r) * W2S + ks * 32 + g * 8];
                acc2[nt] = __builtin_amdgcn_mfma_f32_16x16x32_bf16(w, hb[ks], acc2[nt], 0, 0, 0);
            }
        }

        // ---- relu + f32x4 store ----
        float* ob = out + (size_t)e * D;
        #pragma unroll
        for (int nt = 0; nt < 8; ++nt) {
            f32x4 v = acc2[nt];
            v[0] = v[0] > 0.f ? v[0] : 0.f;
            v[1] = v[1] > 0.f ? v[1] : 0.f;
            v[2] = v[2] > 0.f ? v[2] : 0.f;
            v[3] = v[3] > 0.f ? v[3] : 0.f;
            *(f32x4*)&ob[nt * 16 + g * 4] = v;
        }

        // ---- rotate pipeline ----
        e = en; dist = distN;
        #pragma unroll
        for (int ks = 0; ks < 4; ++ks) { uf[ks] = ufN[ks]; vf[ks] = vfN[ks]; }
    }
}

extern "C" void kernel_launch(void* const* d_in, const int* in_sizes, int n_in,
                              void* d_out, int out_size, void* d_ws, size_t ws_size,
                              hipStream_t stream) {
    const float* node_features = (const float*)d_in[0];
    const float* node_hidden   = (const float*)d_in[1];
    const float* distance      = (const float*)d_in[2];
    const int*   src_idx       = (const int*)d_in[3];
    const int*   dst_idx       = (const int*)d_in[4];
    const float* W1 = (const float*)d_in[5];
    const float* b1 = (const float*)d_in[6];
    const float* W2 = (const float*)d_in[7];
    const float* b2 = (const float*)d_in[8];
    float* out = (float*)d_out;

    const int wThreads = 2 * WU_ELEMS + W2_ELEMS + D;  // 60544
    prep_w<<<(wThreads + 255) / 256, 256, 0, stream>>>(W1, b1, W2);

    prep_uv<<<(NODE_TILES + 7) / 8, 512, 0, stream>>>(node_hidden, node_features);

    edge_mlp<<<1024, 512, 0, stream>>>(src_idx, dst_idx, distance, b2, out);
}